// Round 4
// baseline (230.031 us; speedup 1.0000x reference)
//
#include <hip/hip_runtime.h>
#include <math.h>

#define NC   1000        // NUM_CLASSES
#define NV4  250         // float4 chunks per row (1000/4)
#define RPW  2           // rows per wave
#define RPB  8           // rows per block (4 waves x 2 rows)

typedef float fvec4 __attribute__((ext_vector_type(4)));

__device__ __forceinline__ float fast_sigmoid(float x) {
    return 1.0f / (1.0f + __expf(-x));   // v_exp_f32 path
}

__global__ __launch_bounds__(256)
void smooth_filter_kernel(const float* __restrict__ in, float* __restrict__ out, int nrows) {
    const int wave = threadIdx.x >> 6;
    const int lane = threadIdx.x & 63;
    const int rowA = blockIdx.x * RPB + wave * RPW;
    const int rowB = rowA + 1;
    if (rowA >= nrows) return;
    const bool hasB = (rowB < nrows);

    const fvec4* __restrict__ rpA = (const fvec4*)(in + (size_t)rowA * NC);
    const fvec4* __restrict__ rpB = (const fvec4*)(in + (size_t)(hasB ? rowB : rowA) * NC);

    // Issue all 8 loads up front for max memory-level parallelism.
    fvec4 vA[4], vB[4];
    #pragma unroll
    for (int j = 0; j < 4; ++j) {
        const int idx = lane + 64 * j;
        vA[j] = (fvec4)(0.f);
        vB[j] = (fvec4)(0.f);
        if (idx < NV4) {
            vA[j] = rpA[idx];
            vB[j] = rpB[idx];
        }
    }

    float sA_r = 0.f, sA_a = 0.f, sA_q = 0.f;
    float sB_r = 0.f, sB_a = 0.f, sB_q = 0.f;
    #pragma unroll
    for (int j = 0; j < 4; ++j) {
        float a0 = fabsf(vA[j].x), a1 = fabsf(vA[j].y), a2 = fabsf(vA[j].z), a3 = fabsf(vA[j].w);
        sA_r += (vA[j].x + vA[j].y) + (vA[j].z + vA[j].w);
        sA_a += (a0 + a1) + (a2 + a3);
        sA_q += (a0 * a0 + a1 * a1) + (a2 * a2 + a3 * a3);
        float b0 = fabsf(vB[j].x), b1 = fabsf(vB[j].y), b2 = fabsf(vB[j].z), b3 = fabsf(vB[j].w);
        sB_r += (vB[j].x + vB[j].y) + (vB[j].z + vB[j].w);
        sB_a += (b0 + b1) + (b2 + b3);
        sB_q += (b0 * b0 + b1 * b1) + (b2 * b2 + b3 * b3);
    }

    // Two interleaved butterfly reductions (6 independent chains hide swizzle latency).
    #pragma unroll
    for (int m = 32; m > 0; m >>= 1) {
        sA_r += __shfl_xor(sA_r, m, 64);
        sB_r += __shfl_xor(sB_r, m, 64);
        sA_a += __shfl_xor(sA_a, m, 64);
        sB_a += __shfl_xor(sB_a, m, 64);
        sA_q += __shfl_xor(sA_q, m, 64);
        sB_q += __shfl_xor(sB_q, m, 64);
    }

    const float c = 1.0f / (NC - 1);

    const float meanA = sA_a * (1.0f / NC);
    const float istdA = rsqrtf((sA_q - (float)NC * meanA * meanA) * c);
    const float meanB = sB_a * (1.0f / NC);
    const float istdB = rsqrtf((sB_q - (float)NC * meanB * meanB) * c);

    fvec4* __restrict__ wpA = (fvec4*)(out + (size_t)rowA * NC);
    #pragma unroll
    for (int j = 0; j < 4; ++j) {
        const int idx = lane + 64 * j;
        if (idx < NV4) {
            fvec4 o;
            o.x = vA[j].x + fast_sigmoid((fabsf(vA[j].x) - meanA) * istdA) * c * (sA_r - (float)NC * vA[j].x);
            o.y = vA[j].y + fast_sigmoid((fabsf(vA[j].y) - meanA) * istdA) * c * (sA_r - (float)NC * vA[j].y);
            o.z = vA[j].z + fast_sigmoid((fabsf(vA[j].z) - meanA) * istdA) * c * (sA_r - (float)NC * vA[j].z);
            o.w = vA[j].w + fast_sigmoid((fabsf(vA[j].w) - meanA) * istdA) * c * (sA_r - (float)NC * vA[j].w);
            wpA[idx] = o;   // normal store: let L2/L3 absorb
        }
    }
    if (hasB) {
        fvec4* __restrict__ wpB = (fvec4*)(out + (size_t)rowB * NC);
        #pragma unroll
        for (int j = 0; j < 4; ++j) {
            const int idx = lane + 64 * j;
            if (idx < NV4) {
                fvec4 o;
                o.x = vB[j].x + fast_sigmoid((fabsf(vB[j].x) - meanB) * istdB) * c * (sB_r - (float)NC * vB[j].x);
                o.y = vB[j].y + fast_sigmoid((fabsf(vB[j].y) - meanB) * istdB) * c * (sB_r - (float)NC * vB[j].y);
                o.z = vB[j].z + fast_sigmoid((fabsf(vB[j].z) - meanB) * istdB) * c * (sB_r - (float)NC * vB[j].z);
                o.w = vB[j].w + fast_sigmoid((fabsf(vB[j].w) - meanB) * istdB) * c * (sB_r - (float)NC * vB[j].w);
                wpB[idx] = o;
            }
        }
    }
}

extern "C" void kernel_launch(void* const* d_in, const int* in_sizes, int n_in,
                              void* d_out, int out_size, void* d_ws, size_t ws_size,
                              hipStream_t stream) {
    const float* in  = (const float*)d_in[0];
    float*       out = (float*)d_out;
    const int nrows  = in_sizes[0] / NC;              // 32768
    const int blocks = (nrows + RPB - 1) / RPB;       // 4096
    smooth_filter_kernel<<<blocks, 256, 0, stream>>>(in, out, nrows);
}